// Round 1
// baseline (4770.691 us; speedup 1.0000x reference)
//
#include <hip/hip_runtime.h>
#include <hip/hip_bf16.h>
#include <stdint.h>

// Problem constants
// B=64 T=64 E=256 S=128 ENC=1024 RNN=1024 ATT=1024 DENSE=8000
// z-GEMM K = ENC + RNN + E = 2304 (A = [ctx | h | x_t])

typedef __attribute__((ext_vector_type(8))) short short8;
typedef __attribute__((ext_vector_type(4))) float floatx4;
typedef __attribute__((ext_vector_type(4))) unsigned short ushortx4;

__device__ __forceinline__ float b2f(unsigned short u) {
    union { unsigned int i; float f; } v; v.i = ((unsigned int)u) << 16; return v.f;
}
__device__ __forceinline__ unsigned short f2b(float f) {
    union { float f; unsigned int i; } v; v.f = f;
    unsigned int r = v.i + 0x7fffu + ((v.i >> 16) & 1u);
    return (unsigned short)(r >> 16);
}
__device__ __forceinline__ float ftanh(float x) {
    x = fminf(15.f, fmaxf(-15.f, x));
    float e = __expf(2.f * x);
    return (e - 1.f) * __builtin_amdgcn_rcpf(e + 1.f);
}
__device__ __forceinline__ float fsig(float x) {
    return __builtin_amdgcn_rcpf(1.f + __expf(-x));
}

// ---------------- generic f32 -> bf16 convert (vectorized) ----------------
__global__ __launch_bounds__(256) void conv_f32_bf16(
    const float* __restrict__ src, unsigned short* __restrict__ dst, int n4)
{
    int i = blockIdx.x * 256 + threadIdx.x;
    if (i < n4) {
        float4 v = ((const float4*)src)[i];
        ushortx4 o;
        o[0] = f2b(v.x); o[1] = f2b(v.y); o[2] = f2b(v.z); o[3] = f2b(v.w);
        ((ushortx4*)dst)[i] = o;
    }
}

// ------------- transpose + convert: src[K][N] f32 -> dst[N][K] bf16 -------
// grid: (Ncols/32, Krows/32), block 256
__global__ __launch_bounds__(256) void transpose_conv(
    const float* __restrict__ src, int srcld,
    unsigned short* __restrict__ dst, int dstld, int coloff)
{
    __shared__ float tile[32][33];
    const int k0 = blockIdx.y * 32, n0 = blockIdx.x * 32;
    const int r = threadIdx.x >> 3, c = (threadIdx.x & 7) * 4;
    float4 v = *(const float4*)&src[(size_t)(k0 + r) * srcld + n0 + c];
    tile[r][c + 0] = v.x; tile[r][c + 1] = v.y;
    tile[r][c + 2] = v.z; tile[r][c + 3] = v.w;
    __syncthreads();
    const int nr = threadIdx.x >> 3, kc = (threadIdx.x & 7) * 4;
    ushortx4 o;
    o[0] = f2b(tile[kc + 0][nr]);
    o[1] = f2b(tile[kc + 1][nr]);
    o[2] = f2b(tile[kc + 2][nr]);
    o[3] = f2b(tile[kc + 3][nr]);
    *(ushortx4*)&dst[(size_t)(n0 + nr) * dstld + coloff + k0 + kc] = o;
}

// ---------------- bf16 MFMA GEMM, 64x64 tile, 4 waves --------------------
// A [M][K] row-major bf16 (lda), BT [N][K] row-major bf16 (ldbt).
// C[m][n] = sum_k A[m][k]*BT[n][k] (+bias[n]); store fp32 (Cf) or bf16 (Cb).
// grid: (N/64, M/64), block 256.
__global__ __launch_bounds__(256) void gemm_bf16_64(
    const unsigned short* __restrict__ A, int lda,
    const unsigned short* __restrict__ BT, int ldbt,
    int K,
    float* __restrict__ Cf, unsigned short* __restrict__ Cb, int ldc,
    const float* __restrict__ bias)
{
    __shared__ __align__(16) unsigned short As[64 * 32];
    __shared__ __align__(16) unsigned short Bs[64 * 32];
    const int tid = threadIdx.x;
    const int wave = tid >> 6, lane = tid & 63;
    const int q = lane >> 4, lm = lane & 15;
    const int m0 = blockIdx.y * 64, n0 = blockIdx.x * 64;
    const int sr = tid >> 2, sc = (tid & 3) * 8;
    const unsigned short* Ap = A + (size_t)(m0 + sr) * lda + sc;
    const unsigned short* Bp = BT + (size_t)(n0 + sr) * ldbt + sc;

    floatx4 acc0 = {0.f,0.f,0.f,0.f}, acc1 = {0.f,0.f,0.f,0.f};
    floatx4 acc2 = {0.f,0.f,0.f,0.f}, acc3 = {0.f,0.f,0.f,0.f};
    const int aoff = (wave * 16 + lm) * 32 + q * 8;

    for (int kb = 0; kb < K; kb += 32) {
        *(uint4*)&As[sr * 32 + sc] = *(const uint4*)(Ap + kb);
        *(uint4*)&Bs[sr * 32 + sc] = *(const uint4*)(Bp + kb);
        __syncthreads();
        short8 a  = *(const short8*)&As[aoff];
        short8 b0 = *(const short8*)&Bs[(0 * 16 + lm) * 32 + q * 8];
        short8 b1 = *(const short8*)&Bs[(1 * 16 + lm) * 32 + q * 8];
        short8 b2 = *(const short8*)&Bs[(2 * 16 + lm) * 32 + q * 8];
        short8 b3 = *(const short8*)&Bs[(3 * 16 + lm) * 32 + q * 8];
        acc0 = __builtin_amdgcn_mfma_f32_16x16x32_bf16(a, b0, acc0, 0, 0, 0);
        acc1 = __builtin_amdgcn_mfma_f32_16x16x32_bf16(a, b1, acc1, 0, 0, 0);
        acc2 = __builtin_amdgcn_mfma_f32_16x16x32_bf16(a, b2, acc2, 0, 0, 0);
        acc3 = __builtin_amdgcn_mfma_f32_16x16x32_bf16(a, b3, acc3, 0, 0, 0);
        __syncthreads();
    }
    const int rbase = m0 + wave * 16 + q * 4;
    floatx4 accs[4] = {acc0, acc1, acc2, acc3};
#pragma unroll
    for (int i = 0; i < 4; i++) {
        int col = n0 + i * 16 + lm;
        float bv = bias ? bias[col] : 0.f;
#pragma unroll
        for (int r = 0; r < 4; r++) {
            float v = accs[i][r] + bv;
            size_t idx = (size_t)(rbase + r) * ldc + col;
            if (Cf) Cf[idx] = v;
            if (Cb) Cb[idx] = f2b(v);
        }
    }
}

// -------------------- init h/c state --------------------
__global__ __launch_bounds__(256) void init_hc(
    const float* __restrict__ hidden, const float* __restrict__ cell,
    float* __restrict__ hf, float* __restrict__ cb, unsigned short* __restrict__ Acomb)
{
    int idx = blockIdx.x * 256 + threadIdx.x;  // < 65536
    float h = hidden[idx], c = cell[idx];
    hf[idx] = h; cb[idx] = c;
    Acomb[(idx >> 10) * 2304 + 1024 + (idx & 1023)] = f2b(h);
}

// ------------- attention scores: sc[b,s] = V . tanh(q[b]+keys[b,s]) + bV --
// grid (32, 64): blockIdx.y = b, 4 s per block (one per wave)
__global__ __launch_bounds__(256) void attn_scores(
    const float* __restrict__ qv, const unsigned short* __restrict__ keys,
    const float* __restrict__ V, const float* __restrict__ bV,
    float* __restrict__ sc)
{
    const int b = blockIdx.y;
    const int wave = threadIdx.x >> 6, lane = threadIdx.x & 63;
    const int s = blockIdx.x * 4 + wave;
    const float4* q4 = (const float4*)(qv + b * 1024 + lane * 16);
    const float4* V4 = (const float4*)(V + lane * 16);
    const uint4* kp = (const uint4*)(keys + ((size_t)(b * 128 + s)) * 1024 + lane * 16);
    uint4 k0 = kp[0], k1 = kp[1];
    float kf[16];
    kf[0] = b2f((unsigned short)(k0.x & 0xffff)); kf[1] = b2f((unsigned short)(k0.x >> 16));
    kf[2] = b2f((unsigned short)(k0.y & 0xffff)); kf[3] = b2f((unsigned short)(k0.y >> 16));
    kf[4] = b2f((unsigned short)(k0.z & 0xffff)); kf[5] = b2f((unsigned short)(k0.z >> 16));
    kf[6] = b2f((unsigned short)(k0.w & 0xffff)); kf[7] = b2f((unsigned short)(k0.w >> 16));
    kf[8] = b2f((unsigned short)(k1.x & 0xffff)); kf[9] = b2f((unsigned short)(k1.x >> 16));
    kf[10] = b2f((unsigned short)(k1.y & 0xffff)); kf[11] = b2f((unsigned short)(k1.y >> 16));
    kf[12] = b2f((unsigned short)(k1.z & 0xffff)); kf[13] = b2f((unsigned short)(k1.z >> 16));
    kf[14] = b2f((unsigned short)(k1.w & 0xffff)); kf[15] = b2f((unsigned short)(k1.w >> 16));
    float part = 0.f;
#pragma unroll
    for (int j = 0; j < 4; j++) {
        float4 qa = q4[j]; float4 va = V4[j];
        part += va.x * ftanh(qa.x + kf[j * 4 + 0]);
        part += va.y * ftanh(qa.y + kf[j * 4 + 1]);
        part += va.z * ftanh(qa.z + kf[j * 4 + 2]);
        part += va.w * ftanh(qa.w + kf[j * 4 + 3]);
    }
#pragma unroll
    for (int off = 32; off; off >>= 1) part += __shfl_xor(part, off);
    if (lane == 0) sc[b * 128 + s] = part + bV[0];
}

// ------ softmax over S + ctx = sum_s attn*enc; writes Acomb ctx & x_t -----
// grid (2, 64): blockIdx.y = b, blockIdx.x = e-chunk of 512
__global__ __launch_bounds__(256) void softmax_ctx(
    const float* __restrict__ sc, const unsigned short* __restrict__ enc_bf,
    const unsigned short* __restrict__ x_bf, unsigned short* __restrict__ Acomb, int t)
{
    __shared__ float attnv[128];
    __shared__ float smax, ssum;
    const int b = blockIdx.y, chunk = blockIdx.x, tid = threadIdx.x;
    float sv = 0.f;
    if (tid < 128) { sv = sc[b * 128 + tid]; attnv[tid] = sv; }
    __syncthreads();
    if (tid < 64) {
        float m = fmaxf(attnv[tid], attnv[tid + 64]);
#pragma unroll
        for (int off = 32; off; off >>= 1) m = fmaxf(m, __shfl_xor(m, off));
        if (tid == 0) smax = m;
    }
    __syncthreads();
    float e = 0.f;
    if (tid < 128) { e = __expf(sv - smax); attnv[tid] = e; }
    __syncthreads();
    if (tid < 64) {
        float s2 = attnv[tid] + attnv[tid + 64];
#pragma unroll
        for (int off = 32; off; off >>= 1) s2 += __shfl_xor(s2, off);
        if (tid == 0) ssum = s2;
    }
    if (chunk == 0) {  // stage x_t into Acomb cols 2048..2303
        Acomb[b * 2304 + 2048 + tid] = x_bf[((size_t)b * 64 + t) * 256 + tid];
    }
    __syncthreads();
    const float rs = __builtin_amdgcn_rcpf(ssum);
    const int e0 = chunk * 512 + tid * 2;
    const unsigned int* ep = (const unsigned int*)(enc_bf + (size_t)b * 128 * 1024 + e0);
    float ax = 0.f, ay = 0.f;
#pragma unroll 4
    for (int s = 0; s < 128; s++) {
        float a = attnv[s];
        unsigned int u = ep[s * 512];
        ax += a * b2f((unsigned short)(u & 0xffff));
        ay += a * b2f((unsigned short)(u >> 16));
    }
    ax *= rs; ay *= rs;
    unsigned int pack = (unsigned int)f2b(ax) | ((unsigned int)f2b(ay) << 16);
    *(unsigned int*)&Acomb[b * 2304 + e0] = pack;
}

// -------------------- LSTM gates --------------------
__global__ __launch_bounds__(256) void gates_k(
    const float* __restrict__ z, float* __restrict__ cb, float* __restrict__ hf,
    unsigned short* __restrict__ Acomb, unsigned short* __restrict__ Hall, int t)
{
    int idx = blockIdx.x * 256 + threadIdx.x;  // < 65536
    int b = idx >> 10, r = idx & 1023;
    const float* zr = z + (size_t)b * 4096;
    float ii = fsig(zr[r]);
    float ff = fsig(zr[1024 + r]);
    float gg = ftanh(zr[2048 + r]);
    float oo = fsig(zr[3072 + r]);
    float cn = ff * cb[idx] + ii * gg;
    float hn = oo * ftanh(cn);
    cb[idx] = cn; hf[idx] = hn;
    unsigned short hb = f2b(hn);
    Acomb[b * 2304 + 1024 + r] = hb;
    Hall[((size_t)b * 64 + t) * 1024 + r] = hb;
}

// -------------------- final h/c copy to d_out tail --------------------
__global__ __launch_bounds__(256) void tail_k(
    const float* __restrict__ hf, const float* __restrict__ cb, float* __restrict__ out)
{
    int i = blockIdx.x * 256 + threadIdx.x;  // < 131072
    if (i < 65536) out[32768000 + i] = hf[i];
    else out[32768000 + i] = cb[i - 65536];  // 32768000+65536+(i-65536)
}

// ---------------------------------------------------------------------------
extern "C" void kernel_launch(void* const* d_in, const int* in_sizes, int n_in,
                              void* d_out, int out_size, void* d_ws, size_t ws_size,
                              hipStream_t stream)
{
    const float* x      = (const float*)d_in[0];   // [64,64,256]
    const float* hidden = (const float*)d_in[1];   // [64,1024]
    const float* cell   = (const float*)d_in[2];   // [64,1024]
    const float* enc    = (const float*)d_in[3];   // [64,128,1024]
    const float* W1     = (const float*)d_in[4];   // [1024,1024]
    const float* b1     = (const float*)d_in[5];   // [1024]
    const float* W2     = (const float*)d_in[6];   // [1024,1024]
    const float* b2     = (const float*)d_in[7];   // [1024]
    const float* V      = (const float*)d_in[8];   // [1024]
    const float* bV     = (const float*)d_in[9];   // [1]
    const float* Wk     = (const float*)d_in[10];  // [1280,4096]
    const float* rk     = (const float*)d_in[11];  // [1024,4096]
    const float* bz     = (const float*)d_in[12];  // [4096]
    const float* Wd     = (const float*)d_in[13];  // [1024,8000]
    const float* bd     = (const float*)d_in[14];  // [8000]
    float* out = (float*)d_out;

    char* ws = (char*)d_ws;
    unsigned short* enc_bf  = (unsigned short*)(ws + 0);          // 16,777,216 B
    unsigned short* keys_bf = (unsigned short*)(ws + 16777216);   // 16,777,216 B
    unsigned short* W1T     = (unsigned short*)(ws + 33554432);   //  2,097,152 B
    unsigned short* W2T     = (unsigned short*)(ws + 35651584);   //  2,097,152 B
    unsigned short* BzT     = (unsigned short*)(ws + 37748736);   // 18,874,368 B  [4096][2304]
    unsigned short* WdT     = (unsigned short*)(ws + 56623104);   // 16,384,000 B  [8000][1024]
    unsigned short* x_bf    = (unsigned short*)(ws + 73007360);   //  2,097,152 B (aligned)
    unsigned short* Hall    = (unsigned short*)(ws + 75104512);   //  8,388,608 B  [4096][1024]
    unsigned short* Acomb   = (unsigned short*)(ws + 83493120);   //    294,912 B  [64][2304]
    float* qbuf  = (float*)(ws + 83788032);                       //    262,144 B
    float* zbuf  = (float*)(ws + 84050176);                       //  1,048,576 B
    float* scbuf = (float*)(ws + 85098752);                       //     32,768 B
    float* hf    = (float*)(ws + 85131520);                       //    262,144 B
    float* cb    = (float*)(ws + 85393664);                       //    262,144 B
    // total ~85.7 MB

    // ---- one-time (per call) conversions / transposes ----
    conv_f32_bf16<<<8192, 256, 0, stream>>>(enc, enc_bf, 8388608 / 4);
    conv_f32_bf16<<<1024, 256, 0, stream>>>(x, x_bf, 1048576 / 4);
    transpose_conv<<<dim3(32, 32),  256, 0, stream>>>(W1, 1024, W1T, 1024, 0);
    transpose_conv<<<dim3(32, 32),  256, 0, stream>>>(W2, 1024, W2T, 1024, 0);
    transpose_conv<<<dim3(128, 32), 256, 0, stream>>>(Wk, 4096, BzT, 2304, 0);       // kernel[0:1024] (ctx)
    transpose_conv<<<dim3(128, 32), 256, 0, stream>>>(rk, 4096, BzT, 2304, 1024);    // rkernel
    transpose_conv<<<dim3(128, 8),  256, 0, stream>>>(Wk + 1024 * 4096, 4096, BzT, 2304, 2048); // kernel[1024:1280] (x)
    transpose_conv<<<dim3(250, 32), 256, 0, stream>>>(Wd, 8000, WdT, 1024, 0);
    init_hc<<<256, 256, 0, stream>>>(hidden, cell, hf, cb, Acomb);

    // keys = enc @ W2 + b2  -> bf16 [8192][1024]
    gemm_bf16_64<<<dim3(16, 128), 256, 0, stream>>>(enc_bf, 1024, W2T, 1024, 1024,
                                                    nullptr, keys_bf, 1024, b2);

    // ---- recurrence ----
    for (int t = 0; t < 64; t++) {
        // q = h @ W1 + b1   [64][1024]
        gemm_bf16_64<<<dim3(16, 1), 256, 0, stream>>>(Acomb + 1024, 2304, W1T, 1024, 1024,
                                                      qbuf, nullptr, 1024, b1);
        attn_scores<<<dim3(32, 64), 256, 0, stream>>>(qbuf, keys_bf, V, bV, scbuf);
        softmax_ctx<<<dim3(2, 64), 256, 0, stream>>>(scbuf, enc_bf, x_bf, Acomb, t);
        // z = [ctx|h|x_t] @ BzT^T + bias   [64][4096]
        gemm_bf16_64<<<dim3(64, 1), 256, 0, stream>>>(Acomb, 2304, BzT, 2304, 2304,
                                                      zbuf, nullptr, 4096, bz);
        gates_k<<<256, 256, 0, stream>>>(zbuf, cb, hf, Acomb, Hall, t);
    }

    // logits = Hall @ Wd + bd -> out [4096][8000]
    gemm_bf16_64<<<dim3(125, 64), 256, 0, stream>>>(Hall, 1024, WdT, 1024, 1024,
                                                    out, nullptr, 8000, bd);
    tail_k<<<512, 256, 0, stream>>>(hf, cb, out);
}

// Round 2
// 3205.867 us; speedup vs baseline: 1.4881x; 1.4881x over previous
//
#include <hip/hip_runtime.h>
#include <hip/hip_bf16.h>
#include <stdint.h>

// B=64 T=64 E=256 S=128 ENC=1024 RNN=1024 ATT=1024 DENSE=8000
// hgemm: h @ [W1 | rkernel]  -> [64][5120]  (q = cols 0..1023, zh = cols 1024..5119)
// zcx  : [ctx|x] @ kernel    -> [64][4096]  (K = 1280)

typedef __attribute__((ext_vector_type(8))) short short8;
typedef __attribute__((ext_vector_type(4))) float floatx4;
typedef __attribute__((ext_vector_type(4))) unsigned short ushortx4;

__device__ __forceinline__ float b2f(unsigned short u) {
    union { unsigned int i; float f; } v; v.i = ((unsigned int)u) << 16; return v.f;
}
__device__ __forceinline__ unsigned short f2b(float f) {
    union { float f; unsigned int i; } v; v.f = f;
    unsigned int r = v.i + 0x7fffu + ((v.i >> 16) & 1u);
    return (unsigned short)(r >> 16);
}
__device__ __forceinline__ float ftanh(float x) {
    x = fminf(15.f, fmaxf(-15.f, x));
    float e = __expf(2.f * x);
    return (e - 1.f) * __builtin_amdgcn_rcpf(e + 1.f);
}
__device__ __forceinline__ float fsig(float x) {
    return __builtin_amdgcn_rcpf(1.f + __expf(-x));
}
// async global->LDS, 16B per lane. LDS dest = wave-uniform base + lane*16.
__device__ __forceinline__ void ld_lds16(const void* g, void* l) {
    __builtin_amdgcn_global_load_lds((const __attribute__((address_space(1))) void*)g,
                                     (__attribute__((address_space(3))) void*)l, 16, 0, 0);
}

// ---------------- f32 -> bf16 convert ----------------
__global__ __launch_bounds__(256) void conv_f32_bf16(
    const float* __restrict__ src, unsigned short* __restrict__ dst, int n4)
{
    int i = blockIdx.x * 256 + threadIdx.x;
    if (i < n4) {
        float4 v = ((const float4*)src)[i];
        ushortx4 o;
        o[0] = f2b(v.x); o[1] = f2b(v.y); o[2] = f2b(v.z); o[3] = f2b(v.w);
        ((ushortx4*)dst)[i] = o;
    }
}

// ------------- transpose + convert: src[K][N] f32 -> dst[N][K] bf16 -------
__global__ __launch_bounds__(256) void transpose_conv(
    const float* __restrict__ src, int srcld,
    unsigned short* __restrict__ dst, int dstld, int coloff)
{
    __shared__ float tile[32][33];
    const int k0 = blockIdx.y * 32, n0 = blockIdx.x * 32;
    const int r = threadIdx.x >> 3, c = (threadIdx.x & 7) * 4;
    float4 v = *(const float4*)&src[(size_t)(k0 + r) * srcld + n0 + c];
    tile[r][c + 0] = v.x; tile[r][c + 1] = v.y;
    tile[r][c + 2] = v.z; tile[r][c + 3] = v.w;
    __syncthreads();
    const int nr = threadIdx.x >> 3, kc = (threadIdx.x & 7) * 4;
    ushortx4 o;
    o[0] = f2b(tile[kc + 0][nr]);
    o[1] = f2b(tile[kc + 1][nr]);
    o[2] = f2b(tile[kc + 2][nr]);
    o[3] = f2b(tile[kc + 3][nr]);
    *(ushortx4*)&dst[(size_t)(n0 + nr) * dstld + coloff + k0 + kc] = o;
}

// ---------------- 128x128 MFMA GEMM with global_load_lds (m97-style) ------
// A [M][K] bf16, BT [N][K] bf16. grid (N/128, M/128), 256 thr.
// XOR swizzle: LDS chunk p of row r holds global k-chunk p^((r>>1)&3) -> 2-way-only bank access.
__global__ __launch_bounds__(256) void gemm_bf16_128(
    const unsigned short* __restrict__ A, int lda,
    const unsigned short* __restrict__ BT, int ldbt, int K,
    float* __restrict__ Cf, unsigned short* __restrict__ Cb,
    int ldc, int ncols, const float* __restrict__ bias)
{
    __shared__ __align__(16) unsigned short As[128 * 32];
    __shared__ __align__(16) unsigned short Bs[128 * 32];
    const int tid = threadIdx.x, wave = tid >> 6, lane = tid & 63;
    const int q = lane >> 4, lm = lane & 15;
    const int wr = wave >> 1, wc = wave & 1;
    const int m0 = blockIdx.y * 128, n0 = blockIdx.x * 128;
    // staging: wave stages rows [wave*32, wave*32+32) of A and B, 16 rows/instr
    const int srow = lane >> 2;
    const int gch = (lane & 3) ^ ((lane >> 3) & 3);   // swizzled global k-chunk
    const unsigned short* Ag0 = A + (size_t)(m0 + wave * 32 + srow) * lda + gch * 8;
    const unsigned short* Ag1 = Ag0 + (size_t)16 * lda;
    const unsigned short* Bg0 = BT + (size_t)(n0 + wave * 32 + srow) * ldbt + gch * 8;
    const unsigned short* Bg1 = Bg0 + (size_t)16 * ldbt;
    unsigned short* Al0 = &As[(wave * 32) * 32];
    unsigned short* Al1 = &As[(wave * 32 + 16) * 32];
    unsigned short* Bl0 = &Bs[(wave * 32) * 32];
    unsigned short* Bl1 = &Bs[(wave * 32 + 16) * 32];

    const floatx4 z4 = {0.f, 0.f, 0.f, 0.f};
    floatx4 acc[4][4];
#pragma unroll
    for (int i = 0; i < 4; i++)
#pragma unroll
        for (int j = 0; j < 4; j++) acc[i][j] = z4;
    const int ach = ((q ^ ((lm >> 1) & 3))) * 8;      // frag read: swizzled chunk

    for (int kb = 0; kb < K; kb += 32) {
        ld_lds16(Ag0 + kb, Al0);
        ld_lds16(Ag1 + kb, Al1);
        ld_lds16(Bg0 + kb, Bl0);
        ld_lds16(Bg1 + kb, Bl1);
        __syncthreads();
        short8 a[4], b[4];
#pragma unroll
        for (int i = 0; i < 4; i++) a[i] = *(const short8*)&As[(wr * 64 + i * 16 + lm) * 32 + ach];
#pragma unroll
        for (int j = 0; j < 4; j++) b[j] = *(const short8*)&Bs[(wc * 64 + j * 16 + lm) * 32 + ach];
#pragma unroll
        for (int i = 0; i < 4; i++)
#pragma unroll
            for (int j = 0; j < 4; j++)
                acc[i][j] = __builtin_amdgcn_mfma_f32_16x16x32_bf16(a[i], b[j], acc[i][j], 0, 0, 0);
        __syncthreads();
    }
    const int rb = m0 + wr * 64 + q * 4;
#pragma unroll
    for (int i = 0; i < 4; i++) {
#pragma unroll
        for (int j = 0; j < 4; j++) {
            int col = n0 + wc * 64 + j * 16 + lm;
            if (col < ncols) {
                float bv = bias ? bias[col] : 0.f;
#pragma unroll
                for (int r = 0; r < 4; r++) {
                    float v = acc[i][j][r] + bv;
                    size_t idx = (size_t)(rb + i * 16 + r) * ldc + col;
                    if (Cf) Cf[idx] = v;
                    if (Cb) Cb[idx] = f2b(v);
                }
            }
        }
    }
}

// ---------------- skinny M=64 GEMM, split-K, f32 partial out --------------
// grid (N/64, 1, SPLIT); Cpart[split][64][ldc]
__global__ __launch_bounds__(256) void gemm64_split(
    const unsigned short* __restrict__ A, int lda,
    const unsigned short* __restrict__ BT, int ldbt,
    int kchunk, float* __restrict__ Cpart, int ldc)
{
    __shared__ __align__(16) unsigned short As[64 * 32];
    __shared__ __align__(16) unsigned short Bs[64 * 32];
    const int tid = threadIdx.x, wave = tid >> 6, lane = tid & 63;
    const int q = lane >> 4, lm = lane & 15;
    const int n0 = blockIdx.x * 64;
    const int k0 = blockIdx.z * kchunk;
    const int srow = lane >> 2;
    const int gch = (lane & 3) ^ ((lane >> 3) & 3);
    const unsigned short* Ag = A + (size_t)(wave * 16 + srow) * lda + k0 + gch * 8;
    const unsigned short* Bg = BT + (size_t)(n0 + wave * 16 + srow) * ldbt + k0 + gch * 8;
    unsigned short* Al = &As[(wave * 16) * 32];
    unsigned short* Bl = &Bs[(wave * 16) * 32];
    const floatx4 z4 = {0.f, 0.f, 0.f, 0.f};
    floatx4 acc0 = z4, acc1 = z4, acc2 = z4, acc3 = z4;
    const int ach = ((q ^ ((lm >> 1) & 3))) * 8;

    for (int kb = 0; kb < kchunk; kb += 32) {
        ld_lds16(Ag + kb, Al);
        ld_lds16(Bg + kb, Bl);
        __syncthreads();
        short8 a  = *(const short8*)&As[(wave * 16 + lm) * 32 + ach];
        short8 b0 = *(const short8*)&Bs[(0 * 16 + lm) * 32 + ach];
        short8 b1 = *(const short8*)&Bs[(1 * 16 + lm) * 32 + ach];
        short8 b2 = *(const short8*)&Bs[(2 * 16 + lm) * 32 + ach];
        short8 b3 = *(const short8*)&Bs[(3 * 16 + lm) * 32 + ach];
        acc0 = __builtin_amdgcn_mfma_f32_16x16x32_bf16(a, b0, acc0, 0, 0, 0);
        acc1 = __builtin_amdgcn_mfma_f32_16x16x32_bf16(a, b1, acc1, 0, 0, 0);
        acc2 = __builtin_amdgcn_mfma_f32_16x16x32_bf16(a, b2, acc2, 0, 0, 0);
        acc3 = __builtin_amdgcn_mfma_f32_16x16x32_bf16(a, b3, acc3, 0, 0, 0);
        __syncthreads();
    }
    float* Cp = Cpart + (size_t)blockIdx.z * 64 * ldc;
    const int rb = wave * 16 + q * 4;
    floatx4 accs[4] = {acc0, acc1, acc2, acc3};
#pragma unroll
    for (int i = 0; i < 4; i++) {
        int col = n0 + i * 16 + lm;
#pragma unroll
        for (int r = 0; r < 4; r++) Cp[(size_t)(rb + r) * ldc + col] = accs[i][r];
    }
}

// -------------------- init h/c state --------------------
__global__ __launch_bounds__(256) void init_hc(
    const float* __restrict__ hidden, const float* __restrict__ cell,
    float* __restrict__ hf, float* __restrict__ cb, unsigned short* __restrict__ hbf)
{
    int idx = blockIdx.x * 256 + threadIdx.x;  // < 65536
    float h = hidden[idx], c = cell[idx];
    hf[idx] = h; cb[idx] = c; hbf[idx] = f2b(h);
}

// ------------- scores: sc[b,s] = V . tanh(q[b]+keys[b,s]) + bV ------------
// q = qzh_part0 + qzh_part1 + b1 (cols 0..1023). grid (32,64), 4 waves x 1 s.
__global__ __launch_bounds__(256) void attn_scores(
    const float* __restrict__ qzh, const float* __restrict__ b1,
    const unsigned short* __restrict__ keys,
    const float* __restrict__ V, const float* __restrict__ bV,
    float* __restrict__ sc)
{
    const int b = blockIdx.y;
    const int wave = threadIdx.x >> 6, lane = threadIdx.x & 63;
    const int s = blockIdx.x * 4 + wave;
    const float4* q0 = (const float4*)(qzh + b * 5120 + lane * 16);
    const float4* q1 = (const float4*)(qzh + 327680 + b * 5120 + lane * 16);
    const float4* B1 = (const float4*)(b1 + lane * 16);
    const float4* V4 = (const float4*)(V + lane * 16);
    const uint4* kp = (const uint4*)(keys + ((size_t)(b * 128 + s)) * 1024 + lane * 16);
    uint4 k0 = kp[0], k1 = kp[1];
    float kf[16];
    kf[0] = b2f((unsigned short)(k0.x & 0xffff)); kf[1] = b2f((unsigned short)(k0.x >> 16));
    kf[2] = b2f((unsigned short)(k0.y & 0xffff)); kf[3] = b2f((unsigned short)(k0.y >> 16));
    kf[4] = b2f((unsigned short)(k0.z & 0xffff)); kf[5] = b2f((unsigned short)(k0.z >> 16));
    kf[6] = b2f((unsigned short)(k0.w & 0xffff)); kf[7] = b2f((unsigned short)(k0.w >> 16));
    kf[8] = b2f((unsigned short)(k1.x & 0xffff)); kf[9] = b2f((unsigned short)(k1.x >> 16));
    kf[10] = b2f((unsigned short)(k1.y & 0xffff)); kf[11] = b2f((unsigned short)(k1.y >> 16));
    kf[12] = b2f((unsigned short)(k1.z & 0xffff)); kf[13] = b2f((unsigned short)(k1.z >> 16));
    kf[14] = b2f((unsigned short)(k1.w & 0xffff)); kf[15] = b2f((unsigned short)(k1.w >> 16));
    float part = 0.f;
#pragma unroll
    for (int j = 0; j < 4; j++) {
        float4 qa = q0[j], qb = q1[j], bb = B1[j], va = V4[j];
        part += va.x * ftanh(qa.x + qb.x + bb.x + kf[j * 4 + 0]);
        part += va.y * ftanh(qa.y + qb.y + bb.y + kf[j * 4 + 1]);
        part += va.z * ftanh(qa.z + qb.z + bb.z + kf[j * 4 + 2]);
        part += va.w * ftanh(qa.w + qb.w + bb.w + kf[j * 4 + 3]);
    }
#pragma unroll
    for (int off = 32; off; off >>= 1) part += __shfl_xor(part, off);
    if (lane == 0) sc[b * 128 + s] = part + bV[0];
}

// ------ softmax over S + ctx; writes Axc = [ctx | x_t] bf16 [64][1280] ----
// grid (4, 64), 128 threads: chunk of 256 enc cols, 2 packed cols/thread.
__global__ __launch_bounds__(128) void softmax_ctx(
    const float* __restrict__ sc, const unsigned short* __restrict__ enc_bf,
    const float* __restrict__ x, unsigned short* __restrict__ Axc, int t)
{
    __shared__ float attnv[128];
    __shared__ float smax, ssum;
    const int b = blockIdx.y, chunk = blockIdx.x, tid = threadIdx.x;
    float sv = sc[b * 128 + tid];
    attnv[tid] = sv;
    __syncthreads();
    if (tid < 64) {
        float m = fmaxf(attnv[tid], attnv[tid + 64]);
#pragma unroll
        for (int off = 32; off; off >>= 1) m = fmaxf(m, __shfl_xor(m, off));
        if (tid == 0) smax = m;
    }
    __syncthreads();
    float e = __expf(sv - smax);
    attnv[tid] = e;
    __syncthreads();
    if (tid < 64) {
        float s2 = attnv[tid] + attnv[tid + 64];
#pragma unroll
        for (int off = 32; off; off >>= 1) s2 += __shfl_xor(s2, off);
        if (tid == 0) ssum = s2;
    }
    if (chunk == 0) {  // stage x_t into Axc cols 1024..1279
        float x0 = x[((size_t)b * 64 + t) * 256 + tid * 2];
        float x1 = x[((size_t)b * 64 + t) * 256 + tid * 2 + 1];
        unsigned int pk = (unsigned int)f2b(x0) | ((unsigned int)f2b(x1) << 16);
        *(unsigned int*)&Axc[b * 1280 + 1024 + tid * 2] = pk;
    }
    __syncthreads();
    const float rs = __builtin_amdgcn_rcpf(ssum);
    const int e0 = chunk * 256 + tid * 2;
    const unsigned int* ep = (const unsigned int*)(enc_bf + (size_t)b * 131072 + e0);
    float ax = 0.f, ay = 0.f;
#pragma unroll 4
    for (int s = 0; s < 128; s++) {
        float a = attnv[s];
        unsigned int u = ep[s * 512];
        ax += a * b2f((unsigned short)(u & 0xffff));
        ay += a * b2f((unsigned short)(u >> 16));
    }
    ax *= rs; ay *= rs;
    *(unsigned int*)&Axc[b * 1280 + e0] =
        (unsigned int)f2b(ax) | ((unsigned int)f2b(ay) << 16);
}

// -------------------- LSTM gates (sums 4 partial z sources + bias) --------
__global__ __launch_bounds__(256) void gates_k(
    const float* __restrict__ qzh, const float* __restrict__ zcxp,
    const float* __restrict__ bz, float* __restrict__ cb, float* __restrict__ hf,
    unsigned short* __restrict__ hbf, unsigned short* __restrict__ Hall, int t)
{
    int idx = blockIdx.x * 256 + threadIdx.x;  // < 65536
    int b = idx >> 10, r = idx & 1023;
    const float* zh0 = qzh + (size_t)b * 5120 + 1024;
    const float* zh1 = qzh + 327680 + (size_t)b * 5120 + 1024;
    const float* zc0 = zcxp + (size_t)b * 4096;
    const float* zc1 = zcxp + 262144 + (size_t)b * 4096;
    float zi = zh0[r] + zh1[r] + zc0[r] + zc1[r] + bz[r];
    float zf = zh0[1024 + r] + zh1[1024 + r] + zc0[1024 + r] + zc1[1024 + r] + bz[1024 + r];
    float zg = zh0[2048 + r] + zh1[2048 + r] + zc0[2048 + r] + zc1[2048 + r] + bz[2048 + r];
    float zo = zh0[3072 + r] + zh1[3072 + r] + zc0[3072 + r] + zc1[3072 + r] + bz[3072 + r];
    float ii = fsig(zi), ff = fsig(zf), gg = ftanh(zg), oo = fsig(zo);
    float cn = ff * cb[idx] + ii * gg;
    float hn = oo * ftanh(cn);
    cb[idx] = cn; hf[idx] = hn;
    unsigned short hb = f2b(hn);
    hbf[idx] = hb;
    Hall[((size_t)b * 64 + t) * 1024 + r] = hb;
}

// -------------------- final h/c copy to d_out tail --------------------
__global__ __launch_bounds__(256) void tail_k(
    const float* __restrict__ hf, const float* __restrict__ cb, float* __restrict__ out)
{
    int i = blockIdx.x * 256 + threadIdx.x;  // < 131072
    if (i < 65536) out[32768000 + i] = hf[i];
    else out[32768000 + i] = cb[i - 65536];
}

// ---------------------------------------------------------------------------
extern "C" void kernel_launch(void* const* d_in, const int* in_sizes, int n_in,
                              void* d_out, int out_size, void* d_ws, size_t ws_size,
                              hipStream_t stream)
{
    const float* x      = (const float*)d_in[0];   // [64,64,256]
    const float* hidden = (const float*)d_in[1];
    const float* cell   = (const float*)d_in[2];
    const float* enc    = (const float*)d_in[3];   // [64,128,1024]
    const float* W1     = (const float*)d_in[4];   // [1024,1024]
    const float* b1     = (const float*)d_in[5];
    const float* W2     = (const float*)d_in[6];   // [1024,1024]
    const float* b2     = (const float*)d_in[7];
    const float* V      = (const float*)d_in[8];   // [1024]
    const float* bV     = (const float*)d_in[9];
    const float* Wk     = (const float*)d_in[10];  // [1280,4096]
    const float* rk     = (const float*)d_in[11];  // [1024,4096]
    const float* bz     = (const float*)d_in[12];  // [4096]
    const float* Wd     = (const float*)d_in[13];  // [1024,8000]
    const float* bd     = (const float*)d_in[14];  // [8000]
    float* out = (float*)d_out;

    char* ws = (char*)d_ws;
    unsigned short* enc_bf  = (unsigned short*)(ws + 0);          // 16,777,216
    unsigned short* keys_bf = (unsigned short*)(ws + 16777216);   // 16,777,216
    unsigned short* WcT     = (unsigned short*)(ws + 33554432);   // 10,485,760 [5120][1024]
    unsigned short* KcT     = (unsigned short*)(ws + 44040192);   // 10,485,760 [4096][1280]
    unsigned short* WdT     = (unsigned short*)(ws + 54525952);   // 16,515,072 [8064][1024]
    unsigned short* Hall    = (unsigned short*)(ws + 71041024);   //  8,388,608 [4096][1024]
    unsigned short* W2T     = Hall;                               // overlap: dead before Hall written
    unsigned short* hbf     = (unsigned short*)(ws + 79429632);   //    131,072 [64][1024]
    unsigned short* Axc     = (unsigned short*)(ws + 79560704);   //    163,840 [64][1280]
    float* qzh   = (float*)(ws + 79724544);                       //  2,621,440 [2][64][5120]
    float* zcxp  = (float*)(ws + 82345984);                       //  2,097,152 [2][64][4096]
    float* scbuf = (float*)(ws + 84443136);                       //     32,768 [64][128]
    float* hf    = (float*)(ws + 84475904);                       //    262,144
    float* cb    = (float*)(ws + 84738048);                       //    262,144
    // total 85,000,192 B

    // ---- one-time conversions / transposes ----
    conv_f32_bf16<<<8192, 256, 0, stream>>>(enc, enc_bf, 8388608 / 4);
    transpose_conv<<<dim3(32, 32),  256, 0, stream>>>(W2, 1024, W2T, 1024, 0);
    transpose_conv<<<dim3(32, 32),  256, 0, stream>>>(W1, 1024, WcT, 1024, 0);          // WcT rows 0..1023
    transpose_conv<<<dim3(128, 32), 256, 0, stream>>>(rk, 4096, WcT + 1024 * 1024, 1024, 0); // rows 1024..5119
    transpose_conv<<<dim3(128, 32), 256, 0, stream>>>(Wk, 4096, KcT, 1280, 0);          // kernel ctx part
    transpose_conv<<<dim3(128, 8),  256, 0, stream>>>(Wk + 1024 * 4096, 4096, KcT, 1280, 1024); // x part
    transpose_conv<<<dim3(250, 32), 256, 0, stream>>>(Wd, 8000, WdT, 1024, 0);
    init_hc<<<256, 256, 0, stream>>>(hidden, cell, hf, cb, hbf);

    // keys = enc @ W2 + b2 -> bf16 [8192][1024]
    gemm_bf16_128<<<dim3(8, 64), 256, 0, stream>>>(enc_bf, 1024, W2T, 1024, 1024,
                                                   nullptr, keys_bf, 1024, 1024, b2);

    // ---- recurrence ----
    for (int t = 0; t < 64; t++) {
        // [q|zh] = h @ [W1|rk], split-K x2 -> qzh partials
        gemm64_split<<<dim3(80, 1, 2), 256, 0, stream>>>(hbf, 1024, WcT, 1024, 512, qzh, 5120);
        attn_scores<<<dim3(32, 64), 256, 0, stream>>>(qzh, b1, keys_bf, V, bV, scbuf);
        softmax_ctx<<<dim3(4, 64), 128, 0, stream>>>(scbuf, enc_bf, x, Axc, t);
        // zcx = [ctx|x] @ kernel, split-K x2 -> zcx partials
        gemm64_split<<<dim3(64, 1, 2), 256, 0, stream>>>(Axc, 1280, KcT, 1280, 640, zcxp, 4096);
        gates_k<<<256, 256, 0, stream>>>(qzh, zcxp, bz, cb, hf, hbf, Hall, t);
    }

    // logits = Hall @ Wd + bd -> out [4096][8000] (N padded to 8064, guarded)
    gemm_bf16_128<<<dim3(63, 32), 256, 0, stream>>>(Hall, 1024, WdT, 1024, 1024,
                                                    out, nullptr, 8000, 8000, bd);
    tail_k<<<512, 256, 0, stream>>>(hf, cb, out);
}